// Round 4
// baseline (88.838 us; speedup 1.0000x reference)
//
#include <hip/hip_runtime.h>
#include <math.h>

#ifndef M_PI
#define M_PI 3.14159265358979323846
#endif

#define NPOLE 32     // N2
#define SLEN 2048    // L
#define NHALF 1024   // L/2

// -------- Kernel 0: pole tables --------
// tabA[h*32+n] = {ar, wim, dt*v00r, dt*v00i}   ar = -Re(w)*dt > 0
// tabB[h*32+n] = dt*{v01r, v01i, v10r, v10i}
// tabC[h*32+n] = dt*v11r
// nyq[h]       = dt*sum_n v00r   (exact k_f[1024] limit; imag ignored by C2R)
__global__ __launch_bounds__(64) void s4_pole_kernel(
    const float* __restrict__ g_log_dt,
    const float* __restrict__ g_log_w_real,
    const float* __restrict__ g_w_imag,
    const float* __restrict__ g_B,
    const float* __restrict__ g_C,
    const float* __restrict__ g_P,
    float4* __restrict__ tabA,
    float4* __restrict__ tabB,
    float*  __restrict__ tabC,
    float*  __restrict__ nyq)
{
    const int h = blockIdx.x;
    const int n = threadIdx.x;           // 0..63, only 0..31 produce
    const float dt = expf(g_log_dt[h]);
    float s = 0.0f;
    if (n < NPOLE) {
        const int idx = h * NPOLE + n;
        const float ar  = expf(g_log_w_real[idx]) * dt;
        const float wim = g_w_imag[idx] * dt;
        const float Br = g_B[2*idx+0], Bi = g_B[2*idx+1];
        const float Cr = g_C[2*idx+0], Ci = g_C[2*idx+1];
        const float Pr = g_P[2*idx+0], Pi = g_P[2*idx+1];
        const float v00r = dt*(Br*Cr - Bi*Ci);
        tabA[idx] = make_float4(ar, wim, v00r, dt*(Br*Ci + Bi*Cr));
        tabB[idx] = make_float4(dt*(Br*Pr + Bi*Pi), dt*(Bi*Pr - Br*Pi),
                                dt*(Pr*Cr - Pi*Ci), dt*(Pr*Ci + Pi*Cr));
        tabC[idx] = dt*(Pr*Pr + Pi*Pi);
        s = v00r;
    }
    #pragma unroll
    for (int off = 32; off > 0; off >>= 1) s += __shfl_down(s, off);
    if (n == 0) nyq[h] = s;
}

// -------- Kernel 1: Cauchy + Woodbury, one m-node per thread --------
// grid = 4*H blocks x 256 thr -> 8 waves/SIMD. Pole reads are wave-uniform
// global loads (L1 broadcast); no LDS, no barriers.
// z = 2i*tan(pi*m/L); 2/(1+omega) = 1 + i*tan(pi*m/L).
__global__ __launch_bounds__(256) void s4_cauchy_kernel(
    const float4* __restrict__ tabA,
    const float4* __restrict__ tabB,
    const float*  __restrict__ tabC,
    float2* __restrict__ kf)
{
    const int h = blockIdx.x >> 2;
    const int m = ((blockIdx.x & 3) << 8) | threadIdx.x;   // 0..1023
    const float4* __restrict__ pA = tabA + h * NPOLE;
    const float4* __restrict__ pB = tabB + h * NPOLE;
    const float*  __restrict__ pC = tabC + h * NPOLE;

    const float t  = tanf((float)m * (float)(M_PI / 2048.0));
    const float t2 = t + t;

    float r00r=0.f, r00i=0.f, r01r=0.f, r01i=0.f;
    float r10r=0.f, r10i=0.f, r11r=0.f, r11i=0.f;

    #pragma unroll 8
    for (int n = 0; n < NPOLE; ++n) {
        const float4 a  = pA[n];
        const float4 b  = pB[n];
        const float v11 = pC[n];
        const float ar = a.x, wim = a.y;
        const float ar2 = ar * ar;
        float aim = t2 - wim, aip = t2 + wim;
        float inv1 = __builtin_amdgcn_rcpf(fmaf(aim, aim, ar2));
        float inv2 = __builtin_amdgcn_rcpf(fmaf(aip, aip, ar2));
        float d1r = ar * inv1,   e2r = ar * inv2;
        float d1i = -aim * inv1, e2i = -aip * inv2;
        float Sr = d1r + e2r, Dr = d1r - e2r;
        float Si = d1i + e2i, Di = e2i - d1i;
        r00r = fmaf(a.z, Sr, fmaf(a.w, Di, r00r));
        r00i = fmaf(a.z, Si, fmaf(a.w, Dr, r00i));
        r01r = fmaf(b.x, Sr, fmaf(b.y, Di, r01r));
        r01i = fmaf(b.x, Si, fmaf(b.y, Dr, r01i));
        r10r = fmaf(b.z, Sr, fmaf(b.w, Di, r10r));
        r10i = fmaf(b.z, Si, fmaf(b.w, Dr, r10i));
        r11r = fmaf(v11, Sr, r11r);
        r11i = fmaf(v11, Si, r11i);
    }

    // Woodbury + spectral factor (1 + i*t)
    float wdr = 1.0f + r11r, wdi = r11i;
    float winv = __builtin_amdgcn_rcpf(fmaf(wdr, wdr, wdi*wdi));
    float trm = r01r*r10r - r01i*r10i;
    float tim = r01r*r10i + r01i*r10r;
    float cr = (trm*wdr + tim*wdi) * winv;
    float ci = (tim*wdr - trm*wdi) * winv;
    float kr = r00r - cr, ki = r00i - ci;
    kf[h * NHALF + m] = make_float2(fmaf(-ki, t, kr), fmaf(kr, t, ki));
}

// -------- Kernel 2: hermitian pack + N=1024 Stockham IFFT (validated) --------
__global__ __launch_bounds__(256) void s4_ifft_kernel(
    const float2* __restrict__ kf,
    const float*  __restrict__ nyq,
    float* __restrict__ g_out)
{
    const int h   = blockIdx.x;
    const int tid = threadIdx.x;

    __shared__ __align__(16) float2 bufA[NHALF];
    __shared__ __align__(16) float2 bufB[NHALF];
    __shared__ float2 stw[512];       // e^{+i*pi*k/512}

    const float2* __restrict__ X = kf + (size_t)h * NHALF;
    const float nyqv = nyq[h];

    for (int k = tid; k < 512; k += 256) {
        float ang = (float)(M_PI / 512.0) * (float)k;
        float sn, cs;
        sincosf(ang, &sn, &cs);
        stw[k] = make_float2(cs, sn);
    }

    // hermitian pack: E + i*O with O twiddled by e^{+2pi i l/L}
    #pragma unroll
    for (int jj = 0; jj < 4; ++jj) {
        const int l = tid + (jj << 8);
        float2 Xm = X[l];
        float2 Xn = (l == 0) ? make_float2(nyqv, 0.0f) : X[NHALF - l];
        if (l == 0) Xm.y = 0.0f;      // numpy C2R: DC imag ignored
        float er  = 0.5f*(Xm.x + Xn.x);
        float ei  = 0.5f*(Xm.y - Xn.y);
        float odr = 0.5f*(Xm.x - Xn.x);
        float odi = 0.5f*(Xm.y + Xn.y);
        float ang = (float)(M_PI/1024.0) * (float)l;
        float sn, cs;
        sincosf(ang, &sn, &cs);
        float Or = odr*cs - odi*sn;
        float Oi = odr*sn + odi*cs;
        bufB[l] = make_float2(er - Oi, ei + Or);
    }
    __syncthreads();

    float2* src = bufB;
    float2* dst = bufA;
    int s = 1;
    for (int t = 0; t < 10; ++t) {
        #pragma unroll
        for (int j = 0; j < 2; ++j) {
            const int i    = tid + (j << 8);      // 0..511
            const int lo   = i & (s - 1);
            const int base = i - lo;              // s*p in [0,512)
            float2 twf = stw[base];
            float2 a = src[i];
            float2 b = src[i + 512];
            float2 sum = make_float2(a.x + b.x, a.y + b.y);
            float2 dif = make_float2(a.x - b.x, a.y - b.y);
            float2 tw  = make_float2(dif.x*twf.x - dif.y*twf.y,
                                     dif.x*twf.y + dif.y*twf.x);
            const int o = base*2 + lo;
            dst[o]     = sum;
            dst[o + s] = tw;
        }
        __syncthreads();
        float2* tmp = src; src = dst; dst = tmp;
        s <<= 1;
    }
    // after 10 swaps result is in src (== bufB)

    const float scale = 1.0f / (float)NHALF;
    float4* outp = (float4*)(g_out + (size_t)h * SLEN);
    #pragma unroll
    for (int l = tid; l < 512; l += 256) {
        const float4 y2 = *((const float4*)&src[2*l]);
        outp[l] = make_float4(y2.x*scale, y2.y*scale, y2.z*scale, y2.w*scale);
    }
}

extern "C" void kernel_launch(void* const* d_in, const int* in_sizes, int n_in,
                              void* d_out, int out_size, void* d_ws, size_t ws_size,
                              hipStream_t stream) {
    const float* log_dt     = (const float*)d_in[0];
    const float* log_w_real = (const float*)d_in[1];
    const float* w_imag     = (const float*)d_in[2];
    const float* B          = (const float*)d_in[3];
    const float* C          = (const float*)d_in[4];
    const float* P          = (const float*)d_in[5];
    const int H = in_sizes[0];   // 512

    char* ws = (char*)d_ws;
    size_t offA = 0;
    size_t offB = offA + (size_t)H * NPOLE * 16;   // float4
    size_t offC = offB + (size_t)H * NPOLE * 16;   // float4
    size_t offN = offC + (size_t)H * NPOLE * 4;    // float
    size_t offK = offN + (((size_t)H * 4 + 15) & ~15ull);  // align 16
    float4* tabA = (float4*)(ws + offA);
    float4* tabB = (float4*)(ws + offB);
    float*  tabC = (float*)(ws + offC);
    float*  nyq  = (float*)(ws + offN);
    float2* kf   = (float2*)(ws + offK);

    s4_pole_kernel<<<H, 64, 0, stream>>>(log_dt, log_w_real, w_imag, B, C, P,
                                         tabA, tabB, tabC, nyq);
    s4_cauchy_kernel<<<H * 4, 256, 0, stream>>>(tabA, tabB, tabC, kf);
    s4_ifft_kernel<<<H, 256, 0, stream>>>(kf, nyq, (float*)d_out);
}

// Round 5
// 83.036 us; speedup vs baseline: 1.0699x; 1.0699x over previous
//
#include <hip/hip_runtime.h>
#include <math.h>

#define NPOLE 32     // N2
#define SLEN 2048    // L
#define NHALF 1024   // L/2

// Fused single kernel: one block (512 threads) per head.
// All angles in this problem are exact dyadic fractions of a revolution, so
// trig uses raw v_sin_f32/v_cos_f32 (input in REVOLUTIONS per gfx950 ISA) --
// 1 instruction each vs ~60-100 for libm sincosf/tanf range reduction.
// Analytic facts (omega on unit circle):
//   z = 2(1-omega)/(1+omega) = 2i*tan(pi*m/L); 2/(1+omega) = 1 + i*tan(pi*m/L)
// Nyquist m=1024 via exact limit dt*sum(Re v00) (imag ignored by numpy C2R).
__global__ __launch_bounds__(512) void s4_nplr_kernel(
    const float* __restrict__ g_log_dt,
    const float* __restrict__ g_log_w_real,
    const float* __restrict__ g_w_imag,
    const float* __restrict__ g_B,
    const float* __restrict__ g_C,
    const float* __restrict__ g_P,
    float* __restrict__ g_out)
{
    const int h   = blockIdx.x;
    const int tid = threadIdx.x;

    __shared__ float4 sA[NPOLE];      // {ar, wim, dt*v00r, dt*v00i}  ar = -Re(w)*dt
    __shared__ float4 sB[NPOLE];      // dt*{v01r, v01i, v10r, v10i}
    __shared__ float  sC[NPOLE];      // dt*v11r
    __shared__ __align__(16) float2 bufA[NHALF];
    __shared__ __align__(16) float2 bufB[NHALF];
    __shared__ float2 stw[512];       // FFT twiddles e^{+i*pi*k/512}
    __shared__ float2 s_kf_last;      // k_f[1024]

    const float dt = expf(g_log_dt[h]);

    if (tid < NPOLE) {
        const int n   = tid;
        const int idx = h * NPOLE + n;
        const float ar  = expf(g_log_w_real[idx]) * dt;   // -Re(w)*dt > 0
        const float wim = g_w_imag[idx] * dt;
        const float Br = g_B[2*idx+0], Bi = g_B[2*idx+1];
        const float Cr = g_C[2*idx+0], Ci = g_C[2*idx+1];
        const float Pr = g_P[2*idx+0], Pi = g_P[2*idx+1];
        // v00=B*C, v01=B*conj(P), v10=P*C, v11=|P|^2 ; dt folded in
        sA[n] = make_float4(ar, wim, dt*(Br*Cr - Bi*Ci), dt*(Br*Ci + Bi*Cr));
        sB[n] = make_float4(dt*(Br*Pr + Bi*Pi), dt*(Bi*Pr - Br*Pi),
                            dt*(Pr*Cr - Pi*Ci), dt*(Pr*Ci + Pi*Cr));
        sC[n] = dt*(Pr*Pr + Pi*Pi);
    }
    // FFT twiddle table: stw[k] = e^{+i*pi*k/512} = cis(2*pi * k/1024)
    {
        const float rev = (float)tid * (1.0f / 1024.0f);
        stw[tid] = make_float2(__builtin_amdgcn_cosf(rev),
                               __builtin_amdgcn_sinf(rev));
    }
    __syncthreads();

    // ---- Phase B: 2 m-nodes per thread (mA = tid, mB = tid+512) ----
    {
        const int mA = tid;
        const int mB = tid + 512;
        // t = tan(pi*m/2048) = sin(rev)/cos(rev), rev = m/4096 in [0, 0.25)
        const float revA = (float)mA * (1.0f / 4096.0f);
        const float revB = (float)mB * (1.0f / 4096.0f);
        const float tA = __builtin_amdgcn_sinf(revA) *
                         __builtin_amdgcn_rcpf(__builtin_amdgcn_cosf(revA));
        const float tB = __builtin_amdgcn_sinf(revB) *
                         __builtin_amdgcn_rcpf(__builtin_amdgcn_cosf(revB));
        const float t2A = tA + tA, t2B = tB + tB;

        float a00r=0.f,a00i=0.f,a01r=0.f,a01i=0.f,a10r=0.f,a10i=0.f,a11r=0.f,a11i=0.f;
        float b00r=0.f,b00i=0.f,b01r=0.f,b01i=0.f,b10r=0.f,b10i=0.f,b11r=0.f,b11i=0.f;

        #pragma unroll 8
        for (int n = 0; n < NPOLE; ++n) {
            const float4 a  = sA[n];
            const float4 b  = sB[n];
            const float v11 = sC[n];
            const float ar = a.x, wim = a.y;
            const float ar2 = ar * ar;
            // node A
            {
                float aim = t2A - wim, aip = t2A + wim;
                float inv1 = __builtin_amdgcn_rcpf(fmaf(aim, aim, ar2));
                float inv2 = __builtin_amdgcn_rcpf(fmaf(aip, aip, ar2));
                float d1r = ar * inv1,   e2r = ar * inv2;
                float d1i = -aim * inv1, e2i = -aip * inv2;
                float Sr = d1r + e2r, Dr = d1r - e2r;
                float Si = d1i + e2i, Di = e2i - d1i;
                a00r = fmaf(a.z, Sr, fmaf(a.w, Di, a00r));
                a00i = fmaf(a.z, Si, fmaf(a.w, Dr, a00i));
                a01r = fmaf(b.x, Sr, fmaf(b.y, Di, a01r));
                a01i = fmaf(b.x, Si, fmaf(b.y, Dr, a01i));
                a10r = fmaf(b.z, Sr, fmaf(b.w, Di, a10r));
                a10i = fmaf(b.z, Si, fmaf(b.w, Dr, a10i));
                a11r = fmaf(v11, Sr, a11r);
                a11i = fmaf(v11, Si, a11i);
            }
            // node B
            {
                float aim = t2B - wim, aip = t2B + wim;
                float inv1 = __builtin_amdgcn_rcpf(fmaf(aim, aim, ar2));
                float inv2 = __builtin_amdgcn_rcpf(fmaf(aip, aip, ar2));
                float d1r = ar * inv1,   e2r = ar * inv2;
                float d1i = -aim * inv1, e2i = -aip * inv2;
                float Sr = d1r + e2r, Dr = d1r - e2r;
                float Si = d1i + e2i, Di = e2i - d1i;
                b00r = fmaf(a.z, Sr, fmaf(a.w, Di, b00r));
                b00i = fmaf(a.z, Si, fmaf(a.w, Dr, b00i));
                b01r = fmaf(b.x, Sr, fmaf(b.y, Di, b01r));
                b01i = fmaf(b.x, Si, fmaf(b.y, Dr, b01i));
                b10r = fmaf(b.z, Sr, fmaf(b.w, Di, b10r));
                b10i = fmaf(b.z, Si, fmaf(b.w, Dr, b10i));
                b11r = fmaf(v11, Sr, b11r);
                b11i = fmaf(v11, Si, b11i);
            }
        }

        // Woodbury + spectral factor (1 + i*t), node A
        {
            float wdr = 1.0f + a11r, wdi = a11i;
            float winv = __builtin_amdgcn_rcpf(fmaf(wdr, wdr, wdi*wdi));
            float trm = a01r*a10r - a01i*a10i;
            float tim = a01r*a10i + a01i*a10r;
            float cr = (trm*wdr + tim*wdi) * winv;
            float ci = (tim*wdr - trm*wdi) * winv;
            float kr = a00r - cr, ki = a00i - ci;
            bufA[mA] = make_float2(fmaf(-ki, tA, kr), fmaf(kr, tA, ki));
        }
        // node B
        {
            float wdr = 1.0f + b11r, wdi = b11i;
            float winv = __builtin_amdgcn_rcpf(fmaf(wdr, wdr, wdi*wdi));
            float trm = b01r*b10r - b01i*b10i;
            float tim = b01r*b10i + b01i*b10r;
            float cr = (trm*wdr + tim*wdi) * winv;
            float ci = (tim*wdr - trm*wdi) * winv;
            float kr = b00r - cr, ki = b00i - ci;
            bufA[mB] = make_float2(fmaf(-ki, tB, kr), fmaf(kr, tB, ki));
        }
    }
    // Nyquist m=1024: exact limit k_f = dt * sum_n Re(v00_n)
    if (tid == 0) {
        float s = 0.0f;
        #pragma unroll
        for (int n = 0; n < NPOLE; ++n) s += sA[n].z;
        s_kf_last = make_float2(s, 0.0f);
    }
    __syncthreads();

    // ---- Phase C1: hermitian pack X[0..1024] -> Y[0..1023] in bufB ----
    for (int l = tid; l < NHALF; l += 512) {
        float2 Xm = bufA[l];
        float2 Xn = (l == 0) ? s_kf_last : bufA[NHALF - l];
        if (l == 0) { Xm.y = 0.0f; Xn.y = 0.0f; }   // numpy C2R: DC/Nyquist imag ignored
        float er  = 0.5f*(Xm.x + Xn.x);
        float ei  = 0.5f*(Xm.y - Xn.y);
        float odr = 0.5f*(Xm.x - Xn.x);
        float odi = 0.5f*(Xm.y + Xn.y);
        // e^{+i*pi*l/1024} = cis(2*pi * l/2048)
        const float rev = (float)l * (1.0f / 2048.0f);
        float cs = __builtin_amdgcn_cosf(rev);
        float sn = __builtin_amdgcn_sinf(rev);
        float Or = odr*cs - odi*sn;
        float Oi = odr*sn + odi*cs;
        bufB[l] = make_float2(er - Oi, ei + Or);
    }
    __syncthreads();

    // ---- Phase C2: Stockham radix-2 inverse FFT, N=1024, 10 stages ----
    float2* src = bufB;
    float2* dst = bufA;
    int s = 1;
    for (int t = 0; t < 10; ++t) {
        const int i    = tid;                 // 0..511
        const int lo   = i & (s - 1);
        const int base = i - lo;              // s*p in [0,512)
        float2 twf = stw[base];
        float2 a = src[i];
        float2 b = src[i + 512];
        float2 sum = make_float2(a.x + b.x, a.y + b.y);
        float2 dif = make_float2(a.x - b.x, a.y - b.y);
        float2 tw  = make_float2(dif.x*twf.x - dif.y*twf.y,
                                 dif.x*twf.y + dif.y*twf.x);
        const int o = base*2 + lo;
        dst[o]     = sum;
        dst[o + s] = tw;
        __syncthreads();
        float2* tmp = src; src = dst; dst = tmp;
        s <<= 1;
    }
    // after 10 swaps the result sits in src (== bufB)

    // ---- store: x[2l] = Re(y[l])/N, x[2l+1] = Im(y[l])/N ; float4/thread ----
    const float scale = 1.0f / (float)NHALF;
    float4* outp = (float4*)(g_out + (size_t)h * SLEN);
    {
        const float4 y2 = *((const float4*)&src[2*tid]);
        outp[tid] = make_float4(y2.x*scale, y2.y*scale, y2.z*scale, y2.w*scale);
    }
}

extern "C" void kernel_launch(void* const* d_in, const int* in_sizes, int n_in,
                              void* d_out, int out_size, void* d_ws, size_t ws_size,
                              hipStream_t stream) {
    const float* log_dt     = (const float*)d_in[0];
    const float* log_w_real = (const float*)d_in[1];
    const float* w_imag     = (const float*)d_in[2];
    const float* B          = (const float*)d_in[3];
    const float* C          = (const float*)d_in[4];
    const float* P          = (const float*)d_in[5];
    float* out = (float*)d_out;
    const int H = in_sizes[0];   // 512
    s4_nplr_kernel<<<H, 512, 0, stream>>>(log_dt, log_w_real, w_imag, B, C, P, out);
}